// Round 8
// baseline (192.618 us; speedup 1.0000x reference)
//
#include <hip/hip_runtime.h>

#define NB 8
#define NN 8192
#define LAT 64
#define NSTEPS 4
#define REPS 3

#define R_OUT 58            // output z rows per block
#define TROWS 64            // tile rows = R_OUT + 6 (halo 3 each side)
#define CHUNKS 142          // ceil(8192/58)

typedef __attribute__((ext_vector_type(8))) short bf16x8;
typedef __attribute__((ext_vector_type(4))) float f32x4;

// native bf16 convert (LLVM fptrunc -> HW cvt; RNE). Do NOT hand-roll bit RNE.
__device__ __forceinline__ unsigned short f2bf(float f) {
    __bf16 h = (__bf16)f;
    union { __bf16 h; unsigned short u; } v; v.h = h;
    return v.u;
}

__device__ __forceinline__ float bf2f(unsigned short u) {
    union { unsigned u; float f; } v; v.u = ((unsigned)u) << 16;
    return v.f;
}

// v_exp_f32 computes 2^x (ISA: D=2^S0). __builtin_amdgcn_exp2f is the direct spelling.
__device__ __forceinline__ float exp2_fast(float x) {
    return __builtin_amdgcn_exp2f(x);
}

// tanh(x) = 1 - 2*rcp(2^(x*2*log2e)+1)   (constants pre-folded)
__device__ __forceinline__ float tanh_fast(float x) {
    return 1.0f - 2.0f * __builtin_amdgcn_rcpf(exp2_fast(x * 2.8853900817779268f) + 1.0f);
}

// sigmoid-GELU: x * sigmoid(1.702 x) = x * rcp(1 + 2^(-1.702*log2e * x))
__device__ __forceinline__ float gelu_fast(float x) {
    return x * __builtin_amdgcn_rcpf(1.0f + exp2_fast(x * -2.4553418f));
}

__device__ __forceinline__ int iclamp(int v, int lo, int hi) {
    return v < lo ? lo : (v > hi ? hi : v);
}

template<bool FIRST, bool WRITE_Z>
__global__ __launch_bounds__(256, 6)   // LDS 25.6KB allows 6 blocks/CU; VGPR cap 512/6=85 > natural 64
void step_kernel(const float* __restrict__ zin,   // u0 when FIRST
                 float* __restrict__ zout,
                 float* __restrict__ out,
                 int step,
                 const float* __restrict__ w_enc,
                 const float* __restrict__ W1, const float* __restrict__ b1,
                 const float* __restrict__ W2, const float* __restrict__ b2,
                 const float* __restrict__ W3, const float* __restrict__ b3,
                 const float* __restrict__ dtp, const float* __restrict__ dxp) {
    // A: X tile [64][128] u16, XOR-swizzled; H2 [64][64] u16 aliases low half
    // B: H1 [64][64] u16, swizzled; flux bf16 [64][64] aliases
    __shared__ __align__(16) unsigned short As[TROWS * 128];   // 16384 B
    __shared__ __align__(16) unsigned short Bs[TROWS * 64];    //  8192 B
    __shared__ __align__(16) float bbuf[3 * 64];               //   768 B

    int t = threadIdx.x;
    int chunk = blockIdx.x;
    int b = blockIdx.y;
    int n0 = chunk * R_OUT;

    int lane = t & 63;
    int wv = t >> 6;           // wave id == output column tile
    int arow = lane & 15;
    int apart = lane >> 4;
    int col = wv * 16 + arow;  // this lane's MLP output column
    int g = t & 3, r = t >> 2; // thread owns tile row r, latent cols [16g,16g+16)
    int rmax = 8194 - n0;      // last tile row holding a real (unclamped) z

    // ---- per-wave weight fragments (registers, L2-cached gather) ----
    bf16x8 w1f[4], w2f[2], w3f[2];
#pragma unroll
    for (int kt = 0; kt < 4; ++kt) {
        bf16x8 w;
#pragma unroll
        for (int e = 0; e < 8; ++e) {
            int k = kt * 32 + apart * 8 + e;
            w[e] = (short)f2bf(W1[k * 64 + col]);
        }
        w1f[kt] = w;
    }
#pragma unroll
    for (int kt = 0; kt < 2; ++kt) {
        bf16x8 wa, wb;
#pragma unroll
        for (int e = 0; e < 8; ++e) {
            int k = kt * 32 + apart * 8 + e;
            wa[e] = (short)f2bf(W2[k * 64 + col]);
            wb[e] = (short)f2bf(W3[k * 64 + col]);
        }
        w2f[kt] = wa;
        w3f[kt] = wb;
    }
    float bb1 = b1[col], bb2 = b2[col], bb3 = b3[col];
    float c = (dtp[0] / (float)REPS) * __builtin_amdgcn_rcpf(dxp[0]);

    // ---- load own z row slice into registers; w_enc scoped locally ----
    float4 z[4];
    float w2sum;
    {
        const float4* w4p = (const float4*)w_enc;
        float4 w4[4];
#pragma unroll
        for (int j = 0; j < 4; ++j) w4[j] = w4p[g * 4 + j];
        float s = 0.f;
#pragma unroll
        for (int j = 0; j < 4; ++j)
            s += w4[j].x * w4[j].x + w4[j].y * w4[j].y + w4[j].z * w4[j].z + w4[j].w * w4[j].w;
        s += __shfl_xor(s, 1);
        s += __shfl_xor(s, 2);
        w2sum = s;

        int gr = iclamp(n0 - 3 + r, 0, NN - 1);
        if (FIRST) {
            float u = zin[(long)b * NN + gr];
#pragma unroll
            for (int j = 0; j < 4; ++j) {
                z[j].x = u * w4[j].x; z[j].y = u * w4[j].y;
                z[j].z = u * w4[j].z; z[j].w = u * w4[j].w;
            }
            int n = n0 + r - 3;
            if (g == 0 && r >= 3 && r < 3 + R_OUT && n < NN)
                out[(long)b * NSTEPS * NN + n] = u * (w2sum / (w2sum + 1e-8f));
        } else {
            const float4* zp = (const float4*)(zin + ((long)b * NN + gr) * 64 + g * 16);
#pragma unroll
            for (int j = 0; j < 4; ++j) z[j] = zp[j];
        }
    }

    // ---- 3 ghost-boundary sub-steps ----
    for (int rep = 0; rep < REPS; ++rep) {
        // boundary rows (15,31,47) -> bbuf for next wave's zl
        if (lane >= 60 && wv < 3) {
            float4* bp = (float4*)&bbuf[wv * 64 + g * 16];
#pragma unroll
            for (int j = 0; j < 4; ++j) bp[j] = z[j];
        }
        __syncthreads();

        // build X row r: zl = z of row r-1 via shuffle/bbuf (+ edge fixups)
        {
            const float* zf = (const float*)z;
            float zl[16];
#pragma unroll
            for (int k = 0; k < 16; ++k) zl[k] = __shfl_up(zf[k], 4);
            if (lane < 4 && wv > 0) {
                const float4* bp = (const float4*)&bbuf[(wv - 1) * 64 + g * 16];
#pragma unroll
                for (int j = 0; j < 4; ++j) *(float4*)&zl[j * 4] = bp[j];
            }
            if (chunk == 0 && r <= 3) {
#pragma unroll
                for (int k = 0; k < 16; ++k) zl[k] = zf[k];
            }
            bool zrFix = (r > rmax);   // last chunk: ghost beyond domain edge
            union P { int4 v; unsigned short s[8]; } p0, p1, p2, p3;
#pragma unroll
            for (int k = 0; k < 8; ++k) {
                float zra = zrFix ? zl[k] : zf[k];
                float zrb = zrFix ? zl[8 + k] : zf[8 + k];
                p0.s[k] = f2bf(zl[k] + zra);
                p1.s[k] = f2bf(zl[8 + k] + zrb);
                p2.s[k] = f2bf(fabsf(zl[k] - zra));
                p3.s[k] = f2bf(fabsf(zl[8 + k] - zrb));
            }
            int rb = r & 7;
            *(int4*)&As[r * 128 + (((g * 2    ) ^ rb) << 3)] = p0.v;
            *(int4*)&As[r * 128 + (((g * 2 + 1) ^ rb) << 3)] = p1.v;
            *(int4*)&As[r * 128 + (((g * 2 + 8) ^ rb) << 3)] = p2.v;
            *(int4*)&As[r * 128 + (((g * 2 + 9) ^ rb) << 3)] = p3.v;
        }
        __syncthreads();

        // layer 1: X(A) -> H1(B)
#pragma unroll
        for (int rt = 0; rt < 4; ++rt) {
            f32x4 acc = (f32x4){0.f, 0.f, 0.f, 0.f};
#pragma unroll
            for (int kt = 0; kt < 4; ++kt) {
                int ch = (kt * 4 + apart) ^ (arow & 7);
                bf16x8 a = *(const bf16x8*)&As[(rt * 16 + arow) * 128 + (ch << 3)];
                acc = __builtin_amdgcn_mfma_f32_16x16x32_bf16(a, w1f[kt], acc, 0, 0, 0);
            }
#pragma unroll
            for (int rr = 0; rr < 4; ++rr) {
                int row = rt * 16 + apart * 4 + rr;
                int ch = (wv * 2 + (arow >> 3)) ^ (row & 7);
                Bs[(row << 6) + (ch << 3) + (arow & 7)] = f2bf(gelu_fast(acc[rr] + bb1));
            }
        }
        __syncthreads();

        // layer 2: H1(B) -> H2(A, 64-pitch)
#pragma unroll
        for (int rt = 0; rt < 4; ++rt) {
            f32x4 acc = (f32x4){0.f, 0.f, 0.f, 0.f};
#pragma unroll
            for (int kt = 0; kt < 2; ++kt) {
                int ch = (kt * 4 + apart) ^ (arow & 7);
                bf16x8 a = *(const bf16x8*)&Bs[((rt * 16 + arow) << 6) + (ch << 3)];
                acc = __builtin_amdgcn_mfma_f32_16x16x32_bf16(a, w2f[kt], acc, 0, 0, 0);
            }
#pragma unroll
            for (int rr = 0; rr < 4; ++rr) {
                int row = rt * 16 + apart * 4 + rr;
                int ch = (wv * 2 + (arow >> 3)) ^ (row & 7);
                As[(row << 6) + (ch << 3) + (arow & 7)] = f2bf(gelu_fast(acc[rr] + bb2));
            }
        }
        __syncthreads();

        // layer 3 + tanh*0.25: H2(A) -> flux bf16 (B)
#pragma unroll
        for (int rt = 0; rt < 4; ++rt) {
            f32x4 acc = (f32x4){0.f, 0.f, 0.f, 0.f};
#pragma unroll
            for (int kt = 0; kt < 2; ++kt) {
                int ch = (kt * 4 + apart) ^ (arow & 7);
                bf16x8 a = *(const bf16x8*)&As[((rt * 16 + arow) << 6) + (ch << 3)];
                acc = __builtin_amdgcn_mfma_f32_16x16x32_bf16(a, w3f[kt], acc, 0, 0, 0);
            }
#pragma unroll
            for (int rr = 0; rr < 4; ++rr) {
                int row = rt * 16 + apart * 4 + rr;
                int ch = (wv * 2 + (arow >> 3)) ^ (row & 7);
                Bs[(row << 6) + (ch << 3) + (arow & 7)] = f2bf(tanh_fast(acc[rr] + bb3) * 0.25f);
            }
        }
        __syncthreads();

        // update own z (registers) from flux rows r, r+1
        if (r >= rep + 1 && r < TROWS - 1 - rep) {
            int rb0 = r & 7, rb1 = (r + 1) & 7;
            union P { int4 v; unsigned short s[8]; } a0, a1, h0, h1;
            a0.v = *(const int4*)&Bs[( r      << 6) + (((g * 2    ) ^ rb0) << 3)];
            a1.v = *(const int4*)&Bs[( r      << 6) + (((g * 2 + 1) ^ rb0) << 3)];
            h0.v = *(const int4*)&Bs[((r + 1) << 6) + (((g * 2    ) ^ rb1) << 3)];
            h1.v = *(const int4*)&Bs[((r + 1) << 6) + (((g * 2 + 1) ^ rb1) << 3)];
            float* zp = (float*)z;
#pragma unroll
            for (int k = 0; k < 8; ++k) {
                zp[k]     -= c * (bf2f(h0.s[k]) - bf2f(a0.s[k]));
                zp[8 + k] -= c * (bf2f(h1.s[k]) - bf2f(a1.s[k]));
            }
        }
    }

    // ---- decode + optional z writeback (owned rows only, registers) ----
    {
        int n = n0 + r - 3;
        if (r >= 3 && r < 3 + R_OUT && n < NN) {
            const float4* w4p = (const float4*)w_enc;
            float dot = 0.f;
#pragma unroll
            for (int j = 0; j < 4; ++j) {
                float4 w = w4p[g * 4 + j];
                dot += z[j].x * w.x + z[j].y * w.y + z[j].z * w.z + z[j].w * w.w;
            }
            dot += __shfl_xor(dot, 1);
            dot += __shfl_xor(dot, 2);
            if (g == 0)
                out[((long)b * NSTEPS + step) * NN + n] = dot / (w2sum + 1e-8f);
            if (WRITE_Z) {
                float4* zo = (float4*)(zout + ((long)b * NN + n) * 64 + g * 16);
#pragma unroll
                for (int j = 0; j < 4; ++j) zo[j] = z[j];
            }
        }
    }
}

extern "C" void kernel_launch(void* const* d_in, const int* in_sizes, int n_in,
                              void* d_out, int out_size, void* d_ws, size_t ws_size,
                              hipStream_t stream) {
    const float* u0 = (const float*)d_in[0];
    const float* w_enc = (const float*)d_in[1];
    const float* W1 = (const float*)d_in[2];
    const float* b1 = (const float*)d_in[3];
    const float* W2 = (const float*)d_in[4];
    const float* b2 = (const float*)d_in[5];
    const float* W3 = (const float*)d_in[6];
    const float* b3 = (const float*)d_in[7];
    const float* dt = (const float*)d_in[8];
    const float* dx = (const float*)d_in[9];
    float* out = (float*)d_out;

    float* z0 = (float*)d_ws;
    float* z1 = z0 + (size_t)NB * NN * LAT;

    dim3 grid(CHUNKS, NB);
    step_kernel<true, true><<<grid, 256, 0, stream>>>(
        u0, z0, out, 1, w_enc, W1, b1, W2, b2, W3, b3, dt, dx);
    step_kernel<false, true><<<grid, 256, 0, stream>>>(
        z0, z1, out, 2, w_enc, W1, b1, W2, b2, W3, b3, dt, dx);
    step_kernel<false, false><<<grid, 256, 0, stream>>>(
        z1, z0, out, 3, w_enc, W1, b1, W2, b2, W3, b3, dt, dx);
}

// Round 9
// 98.090 us; speedup vs baseline: 1.9637x; 1.9637x over previous
//
#include <hip/hip_runtime.h>

#define NB 8
#define NN 8192
#define LAT 64
#define NSTEPS 4

#define HALO 9              // 9 reps total -> halo 9 each side
#define TROWS 128           // tile rows (= 512 threads / 4)
#define R_OUT 110           // TROWS - 2*HALO
#define CHUNKS 75           // ceil(8192/110)
#define NREPS 9

typedef __attribute__((ext_vector_type(8))) short bf16x8;
typedef __attribute__((ext_vector_type(4))) float f32x4;

// native bf16 convert (LLVM fptrunc -> HW cvt; RNE). Do NOT hand-roll bit RNE.
__device__ __forceinline__ unsigned short f2bf(float f) {
    __bf16 h = (__bf16)f;
    union { __bf16 h; unsigned short u; } v; v.h = h;
    return v.u;
}

__device__ __forceinline__ float bf2f(unsigned short u) {
    union { unsigned u; float f; } v; v.u = ((unsigned)u) << 16;
    return v.f;
}

// v_exp_f32 computes 2^x. __builtin_amdgcn_exp2f is the direct spelling.
__device__ __forceinline__ float exp2_fast(float x) {
    return __builtin_amdgcn_exp2f(x);
}

// tanh(x) = 1 - 2*rcp(2^(x*2*log2e)+1)
__device__ __forceinline__ float tanh_fast(float x) {
    return 1.0f - 2.0f * __builtin_amdgcn_rcpf(exp2_fast(x * 2.8853900817779268f) + 1.0f);
}

// sigmoid-GELU: x * sigmoid(1.702 x) = x * rcp(1 + 2^(-1.702*log2e * x))
__device__ __forceinline__ float gelu_fast(float x) {
    return x * __builtin_amdgcn_rcpf(1.0f + exp2_fast(x * -2.4553418f));
}

__device__ __forceinline__ int iclamp(int v, int lo, int hi) {
    return v < lo ? lo : (v > hi ? hi : v);
}

__global__ __launch_bounds__(512, 4)   // VGPR cap 128: waves_per_eu>=5 spills (r5/r8 post-mortems)
void fused_kernel(const float* __restrict__ u0,
                  float* __restrict__ out,
                  const float* __restrict__ w_enc,
                  const float* __restrict__ W1, const float* __restrict__ b1,
                  const float* __restrict__ W2, const float* __restrict__ b2,
                  const float* __restrict__ W3, const float* __restrict__ b3,
                  const float* __restrict__ dtp, const float* __restrict__ dxp) {
    // As: X tile [128][128] u16 XOR-swizzled; H2 [128][64] aliases low half
    // Bs: H1 [128][64] u16 swizzled; flux bf16 [128][64] aliases
    __shared__ __align__(16) unsigned short As[TROWS * 128];   // 32768 B
    __shared__ __align__(16) unsigned short Bs[TROWS * 64];    // 16384 B
    __shared__ __align__(16) float bbuf[7 * 64];               //  1792 B

    int t = threadIdx.x;
    int chunk = blockIdx.x;
    int b = blockIdx.y;
    int n0 = chunk * R_OUT;

    int lane = t & 63;
    int wv = t >> 6;           // 0..7
    int wc = wv & 3;           // col tile (16 cols)
    int wr = wv >> 2;          // row half (64 rows)
    int arow = lane & 15;
    int apart = lane >> 4;
    int col = wc * 16 + arow;  // this lane's MLP output column
    int g = t & 3, r = t >> 2; // thread owns tile row r (0..127), latent cols [16g,16g+16)
    int rmax = NN - 1 + HALO - n0;   // last tile row holding a real (unclamped) z

    // ---- per-wave weight fragments (registers, L2-cached gather) ----
    bf16x8 w1f[4], w2f[2], w3f[2];
#pragma unroll
    for (int kt = 0; kt < 4; ++kt) {
        bf16x8 w;
#pragma unroll
        for (int e = 0; e < 8; ++e) {
            int k = kt * 32 + apart * 8 + e;
            w[e] = (short)f2bf(W1[k * 64 + col]);
        }
        w1f[kt] = w;
    }
#pragma unroll
    for (int kt = 0; kt < 2; ++kt) {
        bf16x8 wa, wb;
#pragma unroll
        for (int e = 0; e < 8; ++e) {
            int k = kt * 32 + apart * 8 + e;
            wa[e] = (short)f2bf(W2[k * 64 + col]);
            wb[e] = (short)f2bf(W3[k * 64 + col]);
        }
        w2f[kt] = wa;
        w3f[kt] = wb;
    }
    float bb1 = b1[col], bb2 = b2[col], bb3 = b3[col];
    float c = (dtp[0] / 3.0f) * __builtin_amdgcn_rcpf(dxp[0]);

    // ---- encode own z row slice from u0; write step-0 output ----
    float4 z[4];
    float w2sum;
    {
        const float4* w4p = (const float4*)w_enc;
        float4 w4[4];
#pragma unroll
        for (int j = 0; j < 4; ++j) w4[j] = w4p[g * 4 + j];
        float s = 0.f;
#pragma unroll
        for (int j = 0; j < 4; ++j)
            s += w4[j].x * w4[j].x + w4[j].y * w4[j].y + w4[j].z * w4[j].z + w4[j].w * w4[j].w;
        s += __shfl_xor(s, 1);
        s += __shfl_xor(s, 2);
        w2sum = s;

        int n = n0 - HALO + r;
        float u = u0[(long)b * NN + iclamp(n, 0, NN - 1)];
#pragma unroll
        for (int j = 0; j < 4; ++j) {
            z[j].x = u * w4[j].x; z[j].y = u * w4[j].y;
            z[j].z = u * w4[j].z; z[j].w = u * w4[j].w;
        }
        if (g == 0 && r >= HALO && r < HALO + R_OUT && n < NN)
            out[(long)b * NSTEPS * NN + n] = u * (w2sum / (w2sum + 1e-8f));
    }

    // ---- 9 ghost-boundary sub-steps, z resident in registers ----
    for (int rep = 0; rep < NREPS; ++rep) {
        // wave-boundary rows (15,31,...,111) -> bbuf for next wave's zl
        if (lane >= 60 && wv < 7) {
            float4* bp = (float4*)&bbuf[wv * 64 + g * 16];
#pragma unroll
            for (int j = 0; j < 4; ++j) bp[j] = z[j];
        }
        __syncthreads();

        // build X row r: zl = z of row r-1 via shuffle/bbuf (+ edge fixups)
        {
            const float* zf = (const float*)z;
            float zl[16];
#pragma unroll
            for (int k = 0; k < 16; ++k) zl[k] = __shfl_up(zf[k], 4);
            if (lane < 4 && wv > 0) {
                const float4* bp = (const float4*)&bbuf[(wv - 1) * 64 + g * 16];
#pragma unroll
                for (int j = 0; j < 4; ++j) *(float4*)&zl[j * 4] = bp[j];
            }
            if (chunk == 0 && r <= HALO) {
#pragma unroll
                for (int k = 0; k < 16; ++k) zl[k] = zf[k];
            }
            bool zrFix = (r > rmax);   // last chunk: ghost beyond domain edge
            union P { int4 v; unsigned short s[8]; } p0, p1, p2, p3;
#pragma unroll
            for (int k = 0; k < 8; ++k) {
                float zra = zrFix ? zl[k] : zf[k];
                float zrb = zrFix ? zl[8 + k] : zf[8 + k];
                p0.s[k] = f2bf(zl[k] + zra);
                p1.s[k] = f2bf(zl[8 + k] + zrb);
                p2.s[k] = f2bf(fabsf(zl[k] - zra));
                p3.s[k] = f2bf(fabsf(zl[8 + k] - zrb));
            }
            int rb = r & 7;
            *(int4*)&As[r * 128 + (((g * 2    ) ^ rb) << 3)] = p0.v;
            *(int4*)&As[r * 128 + (((g * 2 + 1) ^ rb) << 3)] = p1.v;
            *(int4*)&As[r * 128 + (((g * 2 + 8) ^ rb) << 3)] = p2.v;
            *(int4*)&As[r * 128 + (((g * 2 + 9) ^ rb) << 3)] = p3.v;
        }
        __syncthreads();

        // layer 1: X(As) -> H1(Bs); wave (wr,wc) does rows [wr*64, wr*64+64), its 16 cols
#pragma unroll
        for (int rt = 0; rt < 4; ++rt) {
            f32x4 acc = (f32x4){0.f, 0.f, 0.f, 0.f};
#pragma unroll
            for (int kt = 0; kt < 4; ++kt) {
                int ch = (kt * 4 + apart) ^ (arow & 7);
                bf16x8 a = *(const bf16x8*)&As[(wr * 64 + rt * 16 + arow) * 128 + (ch << 3)];
                acc = __builtin_amdgcn_mfma_f32_16x16x32_bf16(a, w1f[kt], acc, 0, 0, 0);
            }
#pragma unroll
            for (int rr = 0; rr < 4; ++rr) {
                int row = wr * 64 + rt * 16 + apart * 4 + rr;
                int ch = (wc * 2 + (arow >> 3)) ^ (row & 7);
                Bs[(row << 6) + (ch << 3) + (arow & 7)] = f2bf(gelu_fast(acc[rr] + bb1));
            }
        }
        __syncthreads();

        // layer 2: H1(Bs) -> H2(As low half, 64-pitch)
#pragma unroll
        for (int rt = 0; rt < 4; ++rt) {
            f32x4 acc = (f32x4){0.f, 0.f, 0.f, 0.f};
#pragma unroll
            for (int kt = 0; kt < 2; ++kt) {
                int ch = (kt * 4 + apart) ^ (arow & 7);
                bf16x8 a = *(const bf16x8*)&Bs[((wr * 64 + rt * 16 + arow) << 6) + (ch << 3)];
                acc = __builtin_amdgcn_mfma_f32_16x16x32_bf16(a, w2f[kt], acc, 0, 0, 0);
            }
#pragma unroll
            for (int rr = 0; rr < 4; ++rr) {
                int row = wr * 64 + rt * 16 + apart * 4 + rr;
                int ch = (wc * 2 + (arow >> 3)) ^ (row & 7);
                As[(row << 6) + (ch << 3) + (arow & 7)] = f2bf(gelu_fast(acc[rr] + bb2));
            }
        }
        __syncthreads();

        // layer 3 + tanh*0.25: H2(As) -> flux bf16 (Bs)
#pragma unroll
        for (int rt = 0; rt < 4; ++rt) {
            f32x4 acc = (f32x4){0.f, 0.f, 0.f, 0.f};
#pragma unroll
            for (int kt = 0; kt < 2; ++kt) {
                int ch = (kt * 4 + apart) ^ (arow & 7);
                bf16x8 a = *(const bf16x8*)&As[((wr * 64 + rt * 16 + arow) << 6) + (ch << 3)];
                acc = __builtin_amdgcn_mfma_f32_16x16x32_bf16(a, w3f[kt], acc, 0, 0, 0);
            }
#pragma unroll
            for (int rr = 0; rr < 4; ++rr) {
                int row = wr * 64 + rt * 16 + apart * 4 + rr;
                int ch = (wc * 2 + (arow >> 3)) ^ (row & 7);
                Bs[(row << 6) + (ch << 3) + (arow & 7)] = f2bf(tanh_fast(acc[rr] + bb3) * 0.25f);
            }
        }
        __syncthreads();

        // update own z (registers) from flux rows r, r+1; valid window shrinks by 1/side/rep
        if (r >= rep + 1 && r < TROWS - 1 - rep) {
            int rb0 = r & 7, rb1 = (r + 1) & 7;
            union P { int4 v; unsigned short s[8]; } a0, a1, h0, h1;
            a0.v = *(const int4*)&Bs[( r      << 6) + (((g * 2    ) ^ rb0) << 3)];
            a1.v = *(const int4*)&Bs[( r      << 6) + (((g * 2 + 1) ^ rb0) << 3)];
            h0.v = *(const int4*)&Bs[((r + 1) << 6) + (((g * 2    ) ^ rb1) << 3)];
            h1.v = *(const int4*)&Bs[((r + 1) << 6) + (((g * 2 + 1) ^ rb1) << 3)];
            float* zp = (float*)z;
#pragma unroll
            for (int k = 0; k < 8; ++k) {
                zp[k]     -= c * (bf2f(h0.s[k]) - bf2f(a0.s[k]));
                zp[8 + k] -= c * (bf2f(h1.s[k]) - bf2f(a1.s[k]));
            }
        }

        // decode checkpoint after reps 2,5,8 (rows still valid: [rep+1, TROWS-1-rep) ⊇ owned)
        if (rep == 2 || rep == 5 || rep == 8) {
            int n = n0 - HALO + r;
            if (r >= HALO && r < HALO + R_OUT && n < NN) {
                const float4* w4p = (const float4*)w_enc;
                float dot = 0.f;
#pragma unroll
                for (int j = 0; j < 4; ++j) {
                    float4 w = w4p[g * 4 + j];
                    dot += z[j].x * w.x + z[j].y * w.y + z[j].z * w.z + z[j].w * w.w;
                }
                dot += __shfl_xor(dot, 1);
                dot += __shfl_xor(dot, 2);
                if (g == 0) {
                    int step = rep / 3 + 1;
                    out[((long)b * NSTEPS + step) * NN + n] = dot / (w2sum + 1e-8f);
                }
            }
        }
    }
}

extern "C" void kernel_launch(void* const* d_in, const int* in_sizes, int n_in,
                              void* d_out, int out_size, void* d_ws, size_t ws_size,
                              hipStream_t stream) {
    const float* u0 = (const float*)d_in[0];
    const float* w_enc = (const float*)d_in[1];
    const float* W1 = (const float*)d_in[2];
    const float* b1 = (const float*)d_in[3];
    const float* W2 = (const float*)d_in[4];
    const float* b2 = (const float*)d_in[5];
    const float* W3 = (const float*)d_in[6];
    const float* b3 = (const float*)d_in[7];
    const float* dt = (const float*)d_in[8];
    const float* dx = (const float*)d_in[9];
    float* out = (float*)d_out;
    (void)d_ws; (void)ws_size;

    dim3 grid(CHUNKS, NB);
    fused_kernel<<<grid, 512, 0, stream>>>(
        u0, out, w_enc, W1, b1, W2, b2, W3, b3, dt, dx);
}

// Round 10
// 92.856 us; speedup vs baseline: 2.0744x; 1.0564x over previous
//
#include <hip/hip_runtime.h>

#define NB 8
#define NN 8192
#define LAT 64
#define NSTEPS 4

#define HALO 9              // 9 reps total -> halo 9 each side
#define TROWS 128           // tile rows (= 512 threads / 4)
#define R_OUT 110           // TROWS - 2*HALO
#define CHUNKS 75           // ceil(8192/110)
#define NREPS 9

typedef __attribute__((ext_vector_type(8))) short bf16x8;
typedef __attribute__((ext_vector_type(4))) float f32x4;

// native bf16 convert (LLVM fptrunc -> HW cvt; RNE). Do NOT hand-roll bit RNE.
__device__ __forceinline__ unsigned short f2bf(float f) {
    __bf16 h = (__bf16)f;
    union { __bf16 h; unsigned short u; } v; v.h = h;
    return v.u;
}

__device__ __forceinline__ float bf2f(unsigned short u) {
    union { unsigned u; float f; } v; v.u = ((unsigned)u) << 16;
    return v.f;
}

// v_exp_f32 computes 2^x. __builtin_amdgcn_exp2f is the direct spelling.
__device__ __forceinline__ float exp2_fast(float x) {
    return __builtin_amdgcn_exp2f(x);
}

// tanh(x) = 1 - 2*rcp(2^(x*2*log2e)+1)
__device__ __forceinline__ float tanh_fast(float x) {
    return 1.0f - 2.0f * __builtin_amdgcn_rcpf(exp2_fast(x * 2.8853900817779268f) + 1.0f);
}

// sigmoid-GELU: x * sigmoid(1.702 x) = x * rcp(1 + 2^(-1.702*log2e * x))
__device__ __forceinline__ float gelu_fast(float x) {
    return x * __builtin_amdgcn_rcpf(1.0f + exp2_fast(x * -2.4553418f));
}

__device__ __forceinline__ int iclamp(int v, int lo, int hi) {
    return v < lo ? lo : (v > hi ? hi : v);
}

__global__ __launch_bounds__(512, 4)   // compiler VGPR cap 128; waves_per_eu>=5 spills (r5/r8)
void fused_kernel(const float* __restrict__ u0,
                  float* __restrict__ out,
                  const float* __restrict__ w_enc,
                  const float* __restrict__ W1, const float* __restrict__ b1,
                  const float* __restrict__ W2, const float* __restrict__ b2,
                  const float* __restrict__ W3, const float* __restrict__ b3,
                  const float* __restrict__ dtp, const float* __restrict__ dxp) {
    // As: X tile [128][128] u16 XOR-swizzled (chunk granular); H2 [128][64] aliases low half
    // Bs: H1 [128][64] u16 swizzled; flux bf16 [128][64] aliases
    __shared__ __align__(16) unsigned short As[TROWS * 128];   // 32768 B
    __shared__ __align__(16) unsigned short Bs[TROWS * 64];    // 16384 B
    __shared__ __align__(16) float bbuf[7 * 64];               //  1792 B

    int t = threadIdx.x;
    int chunk = blockIdx.x;
    int b = blockIdx.y;
    int n0 = chunk * R_OUT;

    int lane = t & 63;
    int wv = t >> 6;           // 0..7
    int wc = wv & 3;           // col tile (16 cols)
    int wr = wv >> 2;          // row half (64 rows)
    int arow = lane & 15;
    int apart = lane >> 4;
    int g = t & 3, r = t >> 2; // thread owns tile row r (0..127), latent cols [16g,16g+16)
    int rmax = NN - 1 + HALO - n0;   // last tile row holding a real (unclamped) z

    // ---- per-wave weight fragments (registers). With swapped-operand MFMA these are
    // the A-operand: A[m=lane&15][k=(lane>>4)*8+e] = W[k][wc*16+lane&15] — same gather.
    bf16x8 w1f[4], w2f[2], w3f[2];
    {
        int col = wc * 16 + arow;
#pragma unroll
        for (int kt = 0; kt < 4; ++kt) {
            bf16x8 w;
#pragma unroll
            for (int e = 0; e < 8; ++e) {
                int k = kt * 32 + apart * 8 + e;
                w[e] = (short)f2bf(W1[k * 64 + col]);
            }
            w1f[kt] = w;
        }
#pragma unroll
        for (int kt = 0; kt < 2; ++kt) {
            bf16x8 wa, wb;
#pragma unroll
            for (int e = 0; e < 8; ++e) {
                int k = kt * 32 + apart * 8 + e;
                wa[e] = (short)f2bf(W2[k * 64 + col]);
                wb[e] = (short)f2bf(W3[k * 64 + col]);
            }
            w2f[kt] = wa;
            w3f[kt] = wb;
        }
    }
    // biases: lane now owns 4 consecutive output cols = wc*16 + apart*4 + {0..3}
    float4 bb1 = *(const float4*)&b1[wc * 16 + apart * 4];
    float4 bb2 = *(const float4*)&b2[wc * 16 + apart * 4];
    float4 bb3 = *(const float4*)&b3[wc * 16 + apart * 4];
    float c = (dtp[0] / 3.0f) * __builtin_amdgcn_rcpf(dxp[0]);

    // ---- encode own z row slice from u0; write step-0 output ----
    float4 z[4];
    float w2sum;
    {
        const float4* w4p = (const float4*)w_enc;
        float4 w4[4];
#pragma unroll
        for (int j = 0; j < 4; ++j) w4[j] = w4p[g * 4 + j];
        float s = 0.f;
#pragma unroll
        for (int j = 0; j < 4; ++j)
            s += w4[j].x * w4[j].x + w4[j].y * w4[j].y + w4[j].z * w4[j].z + w4[j].w * w4[j].w;
        s += __shfl_xor(s, 1);
        s += __shfl_xor(s, 2);
        w2sum = s;

        int n = n0 - HALO + r;
        float u = u0[(long)b * NN + iclamp(n, 0, NN - 1)];
#pragma unroll
        for (int j = 0; j < 4; ++j) {
            z[j].x = u * w4[j].x; z[j].y = u * w4[j].y;
            z[j].z = u * w4[j].z; z[j].w = u * w4[j].w;
        }
        if (g == 0 && r >= HALO && r < HALO + R_OUT && n < NN)
            out[(long)b * NSTEPS * NN + n] = u * (w2sum / (w2sum + 1e-8f));
    }

    // store helper pieces (constant per thread)
    int stoff = ((apart & 1) << 2);            // in-chunk u16 offset (0 or 4)
    int stch  = wc * 2 + (apart >> 1);         // linear chunk of this lane's 4 cols

    // ---- 9 ghost-boundary sub-steps, z resident in registers ----
    for (int rep = 0; rep < NREPS; ++rep) {
        // wave-boundary rows (15,31,...,111) -> bbuf for next wave's zl
        if (lane >= 60 && wv < 7) {
            float4* bp = (float4*)&bbuf[wv * 64 + g * 16];
#pragma unroll
            for (int j = 0; j < 4; ++j) bp[j] = z[j];
        }
        __syncthreads();

        // build X row r: zl = z of row r-1 via shuffle/bbuf (+ edge fixups)
        {
            const float* zf = (const float*)z;
            float zl[16];
#pragma unroll
            for (int k = 0; k < 16; ++k) zl[k] = __shfl_up(zf[k], 4);
            if (lane < 4 && wv > 0) {
                const float4* bp = (const float4*)&bbuf[(wv - 1) * 64 + g * 16];
#pragma unroll
                for (int j = 0; j < 4; ++j) *(float4*)&zl[j * 4] = bp[j];
            }
            if (chunk == 0 && r <= HALO) {
#pragma unroll
                for (int k = 0; k < 16; ++k) zl[k] = zf[k];
            }
            bool zrFix = (r > rmax);   // last chunk: ghost beyond domain edge
            union P { int4 v; unsigned short s[8]; } p0, p1, p2, p3;
#pragma unroll
            for (int k = 0; k < 8; ++k) {
                float zra = zrFix ? zl[k] : zf[k];
                float zrb = zrFix ? zl[8 + k] : zf[8 + k];
                p0.s[k] = f2bf(zl[k] + zra);
                p1.s[k] = f2bf(zl[8 + k] + zrb);
                p2.s[k] = f2bf(fabsf(zl[k] - zra));
                p3.s[k] = f2bf(fabsf(zl[8 + k] - zrb));
            }
            int rb = r & 7;
            *(int4*)&As[r * 128 + (((g * 2    ) ^ rb) << 3)] = p0.v;
            *(int4*)&As[r * 128 + (((g * 2 + 1) ^ rb) << 3)] = p1.v;
            *(int4*)&As[r * 128 + (((g * 2 + 8) ^ rb) << 3)] = p2.v;
            *(int4*)&As[r * 128 + (((g * 2 + 9) ^ rb) << 3)] = p3.v;
        }
        __syncthreads();

        // layer 1: Hᵀ = mfma(W1, X) ; lane holds row=arow(+tile), 4 consecutive cols -> b64 store
#pragma unroll
        for (int rt = 0; rt < 4; ++rt) {
            int row = wr * 64 + rt * 16 + arow;
            f32x4 acc = (f32x4){0.f, 0.f, 0.f, 0.f};
#pragma unroll
            for (int kt = 0; kt < 4; ++kt) {
                int ch = (kt * 4 + apart) ^ (row & 7);
                bf16x8 x = *(const bf16x8*)&As[(row << 7) + (ch << 3)];
                acc = __builtin_amdgcn_mfma_f32_16x16x32_bf16(w1f[kt], x, acc, 0, 0, 0);
            }
            union { short4 s; int2 v; } pk;
            pk.s.x = (short)f2bf(gelu_fast(acc[0] + bb1.x));
            pk.s.y = (short)f2bf(gelu_fast(acc[1] + bb1.y));
            pk.s.z = (short)f2bf(gelu_fast(acc[2] + bb1.z));
            pk.s.w = (short)f2bf(gelu_fast(acc[3] + bb1.w));
            *(int2*)&Bs[(row << 6) + ((stch ^ (row & 7)) << 3) + stoff] = pk.v;
        }
        __syncthreads();

        // layer 2: H1(Bs) -> H2(As low half, 64-pitch)
#pragma unroll
        for (int rt = 0; rt < 4; ++rt) {
            int row = wr * 64 + rt * 16 + arow;
            f32x4 acc = (f32x4){0.f, 0.f, 0.f, 0.f};
#pragma unroll
            for (int kt = 0; kt < 2; ++kt) {
                int ch = (kt * 4 + apart) ^ (row & 7);
                bf16x8 h = *(const bf16x8*)&Bs[(row << 6) + (ch << 3)];
                acc = __builtin_amdgcn_mfma_f32_16x16x32_bf16(w2f[kt], h, acc, 0, 0, 0);
            }
            union { short4 s; int2 v; } pk;
            pk.s.x = (short)f2bf(gelu_fast(acc[0] + bb2.x));
            pk.s.y = (short)f2bf(gelu_fast(acc[1] + bb2.y));
            pk.s.z = (short)f2bf(gelu_fast(acc[2] + bb2.z));
            pk.s.w = (short)f2bf(gelu_fast(acc[3] + bb2.w));
            *(int2*)&As[(row << 6) + ((stch ^ (row & 7)) << 3) + stoff] = pk.v;
        }
        __syncthreads();

        // layer 3 + tanh*0.25: H2(As) -> flux bf16 (Bs)
#pragma unroll
        for (int rt = 0; rt < 4; ++rt) {
            int row = wr * 64 + rt * 16 + arow;
            f32x4 acc = (f32x4){0.f, 0.f, 0.f, 0.f};
#pragma unroll
            for (int kt = 0; kt < 2; ++kt) {
                int ch = (kt * 4 + apart) ^ (row & 7);
                bf16x8 h = *(const bf16x8*)&As[(row << 6) + (ch << 3)];
                acc = __builtin_amdgcn_mfma_f32_16x16x32_bf16(w3f[kt], h, acc, 0, 0, 0);
            }
            union { short4 s; int2 v; } pk;
            pk.s.x = (short)f2bf(tanh_fast(acc[0] + bb3.x) * 0.25f);
            pk.s.y = (short)f2bf(tanh_fast(acc[1] + bb3.y) * 0.25f);
            pk.s.z = (short)f2bf(tanh_fast(acc[2] + bb3.z) * 0.25f);
            pk.s.w = (short)f2bf(tanh_fast(acc[3] + bb3.w) * 0.25f);
            *(int2*)&Bs[(row << 6) + ((stch ^ (row & 7)) << 3) + stoff] = pk.v;
        }
        __syncthreads();

        // update own z (registers) from flux rows r, r+1; valid window shrinks by 1/side/rep
        if (r >= rep + 1 && r < TROWS - 1 - rep) {
            int rb0 = r & 7, rb1 = (r + 1) & 7;
            union P { int4 v; unsigned short s[8]; } a0, a1, h0, h1;
            a0.v = *(const int4*)&Bs[( r      << 6) + (((g * 2    ) ^ rb0) << 3)];
            a1.v = *(const int4*)&Bs[( r      << 6) + (((g * 2 + 1) ^ rb0) << 3)];
            h0.v = *(const int4*)&Bs[((r + 1) << 6) + (((g * 2    ) ^ rb1) << 3)];
            h1.v = *(const int4*)&Bs[((r + 1) << 6) + (((g * 2 + 1) ^ rb1) << 3)];
            float* zp = (float*)z;
#pragma unroll
            for (int k = 0; k < 8; ++k) {
                zp[k]     -= c * (bf2f(h0.s[k]) - bf2f(a0.s[k]));
                zp[8 + k] -= c * (bf2f(h1.s[k]) - bf2f(a1.s[k]));
            }
        }

        // decode checkpoint after reps 2,5,8
        if (rep == 2 || rep == 5 || rep == 8) {
            int n = n0 - HALO + r;
            if (r >= HALO && r < HALO + R_OUT && n < NN) {
                const float4* w4p = (const float4*)w_enc;
                float dot = 0.f;
#pragma unroll
                for (int j = 0; j < 4; ++j) {
                    float4 w = w4p[g * 4 + j];
                    dot += z[j].x * w.x + z[j].y * w.y + z[j].z * w.z + z[j].w * w.w;
                }
                dot += __shfl_xor(dot, 1);
                dot += __shfl_xor(dot, 2);
                if (g == 0) {
                    int step = rep / 3 + 1;
                    out[((long)b * NSTEPS + step) * NN + n] = dot / (w2sum + 1e-8f);
                }
            }
        }
    }
}

extern "C" void kernel_launch(void* const* d_in, const int* in_sizes, int n_in,
                              void* d_out, int out_size, void* d_ws, size_t ws_size,
                              hipStream_t stream) {
    const float* u0 = (const float*)d_in[0];
    const float* w_enc = (const float*)d_in[1];
    const float* W1 = (const float*)d_in[2];
    const float* b1 = (const float*)d_in[3];
    const float* W2 = (const float*)d_in[4];
    const float* b2 = (const float*)d_in[5];
    const float* W3 = (const float*)d_in[6];
    const float* b3 = (const float*)d_in[7];
    const float* dt = (const float*)d_in[8];
    const float* dx = (const float*)d_in[9];
    float* out = (float*)d_out;
    (void)d_ws; (void)ws_size;

    dim3 grid(CHUNKS, NB);
    fused_kernel<<<grid, 512, 0, stream>>>(
        u0, out, w_enc, W1, b1, W2, b2, W3, b3, dt, dx);
}

// Round 11
// 88.397 us; speedup vs baseline: 2.1790x; 1.0504x over previous
//
#include <hip/hip_runtime.h>

#define NB 8
#define NN 8192
#define LAT 64
#define NSTEPS 4

#define HALO 9              // 9 reps total -> halo 9 each side
#define TROWS 64            // tile rows (= 256 threads / 4)
#define R_OUT 46            // TROWS - 2*HALO
#define CHUNKS 179          // ceil(8192/46)
#define NREPS 9

typedef __attribute__((ext_vector_type(8))) short bf16x8;
typedef __attribute__((ext_vector_type(4))) float f32x4;

// native bf16 convert (LLVM fptrunc -> HW cvt; RNE). Do NOT hand-roll bit RNE.
__device__ __forceinline__ unsigned short f2bf(float f) {
    __bf16 h = (__bf16)f;
    union { __bf16 h; unsigned short u; } v; v.h = h;
    return v.u;
}

__device__ __forceinline__ float bf2f(unsigned short u) {
    union { unsigned u; float f; } v; v.u = ((unsigned)u) << 16;
    return v.f;
}

// v_exp_f32 computes 2^x. __builtin_amdgcn_exp2f is the direct spelling.
__device__ __forceinline__ float exp2_fast(float x) {
    return __builtin_amdgcn_exp2f(x);
}

// tanh(x) = 1 - 2*rcp(2^(x*2*log2e)+1)
__device__ __forceinline__ float tanh_fast(float x) {
    return 1.0f - 2.0f * __builtin_amdgcn_rcpf(exp2_fast(x * 2.8853900817779268f) + 1.0f);
}

// sigmoid-GELU: x * sigmoid(1.702 x) = x * rcp(1 + 2^(-1.702*log2e * x))
__device__ __forceinline__ float gelu_fast(float x) {
    return x * __builtin_amdgcn_rcpf(1.0f + exp2_fast(x * -2.4553418f));
}

__device__ __forceinline__ int iclamp(int v, int lo, int hi) {
    return v < lo ? lo : (v > hi ? hi : v);
}

__global__ __launch_bounds__(256, 4)   // cap 128 VGPR (natural ~64); (256,6)'s 85-cap spilled (r8)
void fused_kernel(const float* __restrict__ u0,
                  float* __restrict__ out,
                  const float* __restrict__ w_enc,
                  const float* __restrict__ W1, const float* __restrict__ b1,
                  const float* __restrict__ W2, const float* __restrict__ b2,
                  const float* __restrict__ W3, const float* __restrict__ b3,
                  const float* __restrict__ dtp, const float* __restrict__ dxp) {
    // As: X tile [64][128] u16 XOR-swizzled (chunk granular); H2 [64][64] aliases low half
    // Bs: H1 [64][64] u16 swizzled; flux bf16 [64][64] aliases
    __shared__ __align__(16) unsigned short As[TROWS * 128];   // 16384 B
    __shared__ __align__(16) unsigned short Bs[TROWS * 64];    //  8192 B
    __shared__ __align__(16) float bbuf[3 * 64];               //   768 B

    int t = threadIdx.x;
    int chunk = blockIdx.x;
    int b = blockIdx.y;
    int n0 = chunk * R_OUT;

    int lane = t & 63;
    int wv = t >> 6;           // 0..3 == output column tile
    int wc = wv;
    int arow = lane & 15;
    int apart = lane >> 4;
    int g = t & 3, r = t >> 2; // thread owns tile row r (0..63), latent cols [16g,16g+16)
    int rmax = NN - 1 + HALO - n0;   // last tile row holding a real (unclamped) z

    // ---- per-wave weight fragments (registers). Swapped-operand MFMA A-operand:
    // A[m=lane&15][k=(lane>>4)*8+e] = W[k][wc*16 + (lane&15)]
    bf16x8 w1f[4], w2f[2], w3f[2];
    {
        int col = wc * 16 + arow;
#pragma unroll
        for (int kt = 0; kt < 4; ++kt) {
            bf16x8 w;
#pragma unroll
            for (int e = 0; e < 8; ++e) {
                int k = kt * 32 + apart * 8 + e;
                w[e] = (short)f2bf(W1[k * 64 + col]);
            }
            w1f[kt] = w;
        }
#pragma unroll
        for (int kt = 0; kt < 2; ++kt) {
            bf16x8 wa, wb;
#pragma unroll
            for (int e = 0; e < 8; ++e) {
                int k = kt * 32 + apart * 8 + e;
                wa[e] = (short)f2bf(W2[k * 64 + col]);
                wb[e] = (short)f2bf(W3[k * 64 + col]);
            }
            w2f[kt] = wa;
            w3f[kt] = wb;
        }
    }
    // biases: lane owns 4 consecutive output cols = wc*16 + apart*4 + {0..3}
    float4 bb1 = *(const float4*)&b1[wc * 16 + apart * 4];
    float4 bb2 = *(const float4*)&b2[wc * 16 + apart * 4];
    float4 bb3 = *(const float4*)&b3[wc * 16 + apart * 4];
    float c = (dtp[0] / 3.0f) * __builtin_amdgcn_rcpf(dxp[0]);

    // ---- encode own z row slice from u0; write step-0 output ----
    float4 z[4];
    float w2sum;
    {
        const float4* w4p = (const float4*)w_enc;
        float4 w4[4];
#pragma unroll
        for (int j = 0; j < 4; ++j) w4[j] = w4p[g * 4 + j];
        float s = 0.f;
#pragma unroll
        for (int j = 0; j < 4; ++j)
            s += w4[j].x * w4[j].x + w4[j].y * w4[j].y + w4[j].z * w4[j].z + w4[j].w * w4[j].w;
        s += __shfl_xor(s, 1);
        s += __shfl_xor(s, 2);
        w2sum = s;

        int n = n0 - HALO + r;
        float u = u0[(long)b * NN + iclamp(n, 0, NN - 1)];
#pragma unroll
        for (int j = 0; j < 4; ++j) {
            z[j].x = u * w4[j].x; z[j].y = u * w4[j].y;
            z[j].z = u * w4[j].z; z[j].w = u * w4[j].w;
        }
        if (g == 0 && r >= HALO && r < HALO + R_OUT && n < NN)
            out[(long)b * NSTEPS * NN + n] = u * (w2sum / (w2sum + 1e-8f));
    }

    // store helper pieces (constant per thread)
    int stoff = ((apart & 1) << 2);            // in-chunk u16 offset (0 or 4)
    int stch  = wc * 2 + (apart >> 1);         // linear chunk of this lane's 4 cols

    // ---- 9 ghost-boundary sub-steps, z resident in registers ----
    for (int rep = 0; rep < NREPS; ++rep) {
        // wave-boundary rows (15,31,47) -> bbuf for next wave's zl
        if (lane >= 60 && wv < 3) {
            float4* bp = (float4*)&bbuf[wv * 64 + g * 16];
#pragma unroll
            for (int j = 0; j < 4; ++j) bp[j] = z[j];
        }
        __syncthreads();

        // build X row r: zl = z of row r-1 via shuffle/bbuf (+ edge fixups)
        {
            const float* zf = (const float*)z;
            float zl[16];
#pragma unroll
            for (int k = 0; k < 16; ++k) zl[k] = __shfl_up(zf[k], 4);
            if (lane < 4 && wv > 0) {
                const float4* bp = (const float4*)&bbuf[(wv - 1) * 64 + g * 16];
#pragma unroll
                for (int j = 0; j < 4; ++j) *(float4*)&zl[j * 4] = bp[j];
            }
            if (chunk == 0 && r <= HALO) {
#pragma unroll
                for (int k = 0; k < 16; ++k) zl[k] = zf[k];
            }
            bool zrFix = (r > rmax);   // last chunk: ghost beyond domain edge
            union P { int4 v; unsigned short s[8]; } p0, p1, p2, p3;
#pragma unroll
            for (int k = 0; k < 8; ++k) {
                float zra = zrFix ? zl[k] : zf[k];
                float zrb = zrFix ? zl[8 + k] : zf[8 + k];
                p0.s[k] = f2bf(zl[k] + zra);
                p1.s[k] = f2bf(zl[8 + k] + zrb);
                p2.s[k] = f2bf(fabsf(zl[k] - zra));
                p3.s[k] = f2bf(fabsf(zl[8 + k] - zrb));
            }
            int rb = r & 7;
            *(int4*)&As[r * 128 + (((g * 2    ) ^ rb) << 3)] = p0.v;
            *(int4*)&As[r * 128 + (((g * 2 + 1) ^ rb) << 3)] = p1.v;
            *(int4*)&As[r * 128 + (((g * 2 + 8) ^ rb) << 3)] = p2.v;
            *(int4*)&As[r * 128 + (((g * 2 + 9) ^ rb) << 3)] = p3.v;
        }
        __syncthreads();

        // layer 1: Hᵀ = mfma(W1, X); lane holds row=arow(+tile), 4 consecutive cols -> b64 store
#pragma unroll
        for (int rt = 0; rt < 4; ++rt) {
            int row = rt * 16 + arow;
            f32x4 acc = (f32x4){0.f, 0.f, 0.f, 0.f};
#pragma unroll
            for (int kt = 0; kt < 4; ++kt) {
                int ch = (kt * 4 + apart) ^ (row & 7);
                bf16x8 x = *(const bf16x8*)&As[(row << 7) + (ch << 3)];
                acc = __builtin_amdgcn_mfma_f32_16x16x32_bf16(w1f[kt], x, acc, 0, 0, 0);
            }
            union { short4 s; int2 v; } pk;
            pk.s.x = (short)f2bf(gelu_fast(acc[0] + bb1.x));
            pk.s.y = (short)f2bf(gelu_fast(acc[1] + bb1.y));
            pk.s.z = (short)f2bf(gelu_fast(acc[2] + bb1.z));
            pk.s.w = (short)f2bf(gelu_fast(acc[3] + bb1.w));
            *(int2*)&Bs[(row << 6) + ((stch ^ (row & 7)) << 3) + stoff] = pk.v;
        }
        __syncthreads();

        // layer 2: H1(Bs) -> H2(As low half, 64-pitch)
#pragma unroll
        for (int rt = 0; rt < 4; ++rt) {
            int row = rt * 16 + arow;
            f32x4 acc = (f32x4){0.f, 0.f, 0.f, 0.f};
#pragma unroll
            for (int kt = 0; kt < 2; ++kt) {
                int ch = (kt * 4 + apart) ^ (row & 7);
                bf16x8 h = *(const bf16x8*)&Bs[(row << 6) + (ch << 3)];
                acc = __builtin_amdgcn_mfma_f32_16x16x32_bf16(w2f[kt], h, acc, 0, 0, 0);
            }
            union { short4 s; int2 v; } pk;
            pk.s.x = (short)f2bf(gelu_fast(acc[0] + bb2.x));
            pk.s.y = (short)f2bf(gelu_fast(acc[1] + bb2.y));
            pk.s.z = (short)f2bf(gelu_fast(acc[2] + bb2.z));
            pk.s.w = (short)f2bf(gelu_fast(acc[3] + bb2.w));
            *(int2*)&As[(row << 6) + ((stch ^ (row & 7)) << 3) + stoff] = pk.v;
        }
        __syncthreads();

        // layer 3 + tanh*0.25: H2(As) -> flux bf16 (Bs)
#pragma unroll
        for (int rt = 0; rt < 4; ++rt) {
            int row = rt * 16 + arow;
            f32x4 acc = (f32x4){0.f, 0.f, 0.f, 0.f};
#pragma unroll
            for (int kt = 0; kt < 2; ++kt) {
                int ch = (kt * 4 + apart) ^ (row & 7);
                bf16x8 h = *(const bf16x8*)&As[(row << 6) + (ch << 3)];
                acc = __builtin_amdgcn_mfma_f32_16x16x32_bf16(w3f[kt], h, acc, 0, 0, 0);
            }
            union { short4 s; int2 v; } pk;
            pk.s.x = (short)f2bf(tanh_fast(acc[0] + bb3.x) * 0.25f);
            pk.s.y = (short)f2bf(tanh_fast(acc[1] + bb3.y) * 0.25f);
            pk.s.z = (short)f2bf(tanh_fast(acc[2] + bb3.z) * 0.25f);
            pk.s.w = (short)f2bf(tanh_fast(acc[3] + bb3.w) * 0.25f);
            *(int2*)&Bs[(row << 6) + ((stch ^ (row & 7)) << 3) + stoff] = pk.v;
        }
        __syncthreads();

        // update own z (registers) from flux rows r, r+1; valid window shrinks by 1/side/rep
        if (r >= rep + 1 && r < TROWS - 1 - rep) {
            int rb0 = r & 7, rb1 = (r + 1) & 7;
            union P { int4 v; unsigned short s[8]; } a0, a1, h0, h1;
            a0.v = *(const int4*)&Bs[( r      << 6) + (((g * 2    ) ^ rb0) << 3)];
            a1.v = *(const int4*)&Bs[( r      << 6) + (((g * 2 + 1) ^ rb0) << 3)];
            h0.v = *(const int4*)&Bs[((r + 1) << 6) + (((g * 2    ) ^ rb1) << 3)];
            h1.v = *(const int4*)&Bs[((r + 1) << 6) + (((g * 2 + 1) ^ rb1) << 3)];
            float* zp = (float*)z;
#pragma unroll
            for (int k = 0; k < 8; ++k) {
                zp[k]     -= c * (bf2f(h0.s[k]) - bf2f(a0.s[k]));
                zp[8 + k] -= c * (bf2f(h1.s[k]) - bf2f(a1.s[k]));
            }
        }

        // decode checkpoint after reps 2,5,8
        if (rep == 2 || rep == 5 || rep == 8) {
            int n = n0 - HALO + r;
            if (r >= HALO && r < HALO + R_OUT && n < NN) {
                const float4* w4p = (const float4*)w_enc;
                float dot = 0.f;
#pragma unroll
                for (int j = 0; j < 4; ++j) {
                    float4 w = w4p[g * 4 + j];
                    dot += z[j].x * w.x + z[j].y * w.y + z[j].z * w.z + z[j].w * w.w;
                }
                dot += __shfl_xor(dot, 1);
                dot += __shfl_xor(dot, 2);
                if (g == 0) {
                    int step = rep / 3 + 1;
                    out[((long)b * NSTEPS + step) * NN + n] = dot / (w2sum + 1e-8f);
                }
            }
        }
    }
}

extern "C" void kernel_launch(void* const* d_in, const int* in_sizes, int n_in,
                              void* d_out, int out_size, void* d_ws, size_t ws_size,
                              hipStream_t stream) {
    const float* u0 = (const float*)d_in[0];
    const float* w_enc = (const float*)d_in[1];
    const float* W1 = (const float*)d_in[2];
    const float* b1 = (const float*)d_in[3];
    const float* W2 = (const float*)d_in[4];
    const float* b2 = (const float*)d_in[5];
    const float* W3 = (const float*)d_in[6];
    const float* b3 = (const float*)d_in[7];
    const float* dt = (const float*)d_in[8];
    const float* dx = (const float*)d_in[9];
    float* out = (float*)d_out;
    (void)d_ws; (void)ws_size;

    dim3 grid(CHUNKS, NB);
    fused_kernel<<<grid, 256, 0, stream>>>(
        u0, out, w_enc, W1, b1, W2, b2, W3, b3, dt, dx);
}